// Round 2
// baseline (2859.698 us; speedup 1.0000x reference)
//
#include <hip/hip_runtime.h>
#include <hip/hip_bf16.h>

// EMD via Sinkhorn (EPS=0.02, 50 iters), B=16, N=M=2048, 3-D points.
// Potentials in base-2 log domain scaled by 1/EPS:
//   u2 = (f/EPS)*log2(e), v2 = (g/EPS)*log2(e)
// Half-iteration: u2[n] = -log2(N) - LSE2_m( v2[m] - d(n,m)*KSCALE )
// Loss: (1/B) * sum_{b,n,m} 2^(u2[n]+v2[m]-d*KSCALE) * d
//
// R1: sink_half was LDS-BW-bound (20 B/elem -> ~26 us/dispatch).
// Now each thread owns 4 rows: one sY/sv read feeds 4 elements (5 B/elem).

#define BATCH 16
#define NPTS 2048
#define RPB 32           // rows per block
#define RPT 4            // rows per thread
#define LPR 32           // lanes per row-group (256 / (RPB/RPT))
#define KSCALE 72.13475204444817f   // (1/0.02) * log2(e)
#define NEG_LOG2N (-11.0f)          // -log2(2048)

#if __has_builtin(__builtin_amdgcn_exp2f)
#define EX2(x) __builtin_amdgcn_exp2f(x)
#else
#define EX2(x) exp2f(x)
#endif
#if __has_builtin(__builtin_amdgcn_logf)
#define LG2(x) __builtin_amdgcn_logf(x)
#else
#define LG2(x) log2f(x)
#endif
#if __has_builtin(__builtin_amdgcn_sqrtf)
#define SQRTF(x) __builtin_amdgcn_sqrtf(x)
#else
#define SQRTF(x) sqrtf(x)
#endif

__global__ __launch_bounds__(256) void prep_kernel(
    const float* __restrict__ tpl, const float* __restrict__ src,
    float4* __restrict__ Xp, float4* __restrict__ Yp, float* __restrict__ v2) {
  int i = blockIdx.x * 256 + threadIdx.x;
  if (i < BATCH * NPTS) {
    float x0 = tpl[3*i], x1 = tpl[3*i+1], x2 = tpl[3*i+2];
    Xp[i] = make_float4(x0, x1, x2, x0*x0 + x1*x1 + x2*x2);
    float y0 = src[3*i], y1 = src[3*i+1], y2 = src[3*i+2];
    Yp[i] = make_float4(y0, y1, y2, y0*y0 + y1*y1 + y2*y2);
    v2[i] = 0.0f;
  }
}

// One Sinkhorn half-step for 32 rows of batch b:
//   wout[n] = -log2(N) - LSE2_m( win[m] - d(n,m)*KSCALE )
// Symmetric: (Xp,Yp,v2,u2) for f-update, (Yp,Xp,u2,v2) for g-update.
__global__ __launch_bounds__(256, 4) void sink_half(
    const float4* __restrict__ Rp,   // points whose potentials we update
    const float4* __restrict__ Cp,   // points scanned (columns)
    const float* __restrict__ win,   // incoming potential (base-2, scaled)
    float* __restrict__ wout) {
  __shared__ float4 sY[NPTS];   // 32 KB
  __shared__ float  sv[NPTS];   // 8 KB
  int bx = blockIdx.x;
  int b = bx >> 6;              // 64 row-blocks per batch
  int rblk = bx & 63;
  int tid = threadIdx.x;
  const float4* cb = Cp + b * NPTS;
  const float*  vb = win + b * NPTS;
  for (int i = tid; i < NPTS; i += 256) { sY[i] = cb[i]; sv[i] = vb[i]; }
  __syncthreads();

  int rg = tid >> 5;            // row-group 0..7
  int lane = tid & 31;          // 32 lanes cover columns
  int nbase = rblk * RPB + rg * RPT;

  float4 xp[RPT];
  float runm[RPT], runs[RPT];
#pragma unroll
  for (int r = 0; r < RPT; ++r) {
    xp[r] = Rp[b * NPTS + nbase + r];
    runm[r] = -1e30f; runs[r] = 0.0f;
  }

  for (int J = 0; J < NPTS / (LPR * 4); ++J) {   // 16 chunk-iterations
    float t[RPT][4];
#pragma unroll
    for (int k = 0; k < 4; ++k) {
      int m = J * 128 + k * 32 + lane;
      float4 yp = sY[m];
      float vm = sv[m];
#pragma unroll
      for (int r = 0; r < RPT; ++r) {
        float dot = fmaf(xp[r].z, yp.z, fmaf(xp[r].y, yp.y, xp[r].x * yp.x));
        float sq  = fmaf(-2.0f, dot, xp[r].w + yp.w);
        float d   = SQRTF(fmaxf(sq, 1e-12f));
        t[r][k] = fmaf(d, -KSCALE, vm);
      }
    }
#pragma unroll
    for (int r = 0; r < RPT; ++r) {
      float tm = fmaxf(fmaxf(t[r][0], t[r][1]), fmaxf(t[r][2], t[r][3]));
      float nm = fmaxf(runm[r], tm);
      float ssum = EX2(t[r][0] - nm) + EX2(t[r][1] - nm)
                 + EX2(t[r][2] - nm) + EX2(t[r][3] - nm);
      runs[r] = fmaf(runs[r], EX2(runm[r] - nm), ssum);
      runm[r] = nm;
    }
  }

  // combine the 32 lanes of this row-group
#pragma unroll
  for (int off = 1; off < LPR; off <<= 1) {
#pragma unroll
    for (int r = 0; r < RPT; ++r) {
      float om = __shfl_xor(runm[r], off);
      float os = __shfl_xor(runs[r], off);
      float nm = fmaxf(runm[r], om);
      runs[r] = fmaf(runs[r], EX2(runm[r] - nm), os * EX2(om - nm));
      runm[r] = nm;
    }
  }
  if (lane == 0) {
#pragma unroll
    for (int r = 0; r < RPT; ++r)
      wout[b * NPTS + nbase + r] = NEG_LOG2N - (runm[r] + LG2(runs[r]));
  }
}

// Final pass: partial[block] = sum over this block's 32 rows of sum_m 2^(u2+v2-d*K)*d
__global__ __launch_bounds__(256, 4) void final_kernel(
    const float4* __restrict__ Xp, const float4* __restrict__ Yp,
    const float* __restrict__ u2, const float* __restrict__ v2,
    float* __restrict__ partials) {
  __shared__ float4 sY[NPTS];
  __shared__ float  sv[NPTS];
  __shared__ float  red[8];
  int bx = blockIdx.x;
  int b = bx >> 6;
  int rblk = bx & 63;
  int tid = threadIdx.x;
  const float4* cb = Yp + b * NPTS;
  const float*  vb = v2 + b * NPTS;
  for (int i = tid; i < NPTS; i += 256) { sY[i] = cb[i]; sv[i] = vb[i]; }
  __syncthreads();

  int rg = tid >> 5;
  int lane = tid & 31;
  int nbase = rblk * RPB + rg * RPT;

  float4 xp[RPT];
  float un[RPT], acc[RPT];
#pragma unroll
  for (int r = 0; r < RPT; ++r) {
    xp[r] = Xp[b * NPTS + nbase + r];
    un[r] = u2[b * NPTS + nbase + r];
    acc[r] = 0.0f;
  }

  for (int J = 0; J < NPTS / (LPR * 4); ++J) {
#pragma unroll
    for (int k = 0; k < 4; ++k) {
      int m = J * 128 + k * 32 + lane;
      float4 yp = sY[m];
      float vm = sv[m];
#pragma unroll
      for (int r = 0; r < RPT; ++r) {
        float dot = fmaf(xp[r].z, yp.z, fmaf(xp[r].y, yp.y, xp[r].x * yp.x));
        float sq  = fmaf(-2.0f, dot, xp[r].w + yp.w);
        float d   = SQRTF(fmaxf(sq, 1e-12f));
        float e   = EX2(fmaf(d, -KSCALE, un[r] + vm));
        acc[r] = fmaf(e, d, acc[r]);
      }
    }
  }
  // reduce 4 rows into one value per thread, then across 32 lanes, then block
  float a = (acc[0] + acc[1]) + (acc[2] + acc[3]);
#pragma unroll
  for (int off = 1; off < LPR; off <<= 1) a += __shfl_xor(a, off);
  if (lane == 0) red[rg] = a;
  __syncthreads();
  if (tid == 0) {
    float s = 0.0f;
#pragma unroll
    for (int i = 0; i < 8; ++i) s += red[i];
    partials[bx] = s;
  }
}

__global__ __launch_bounds__(256) void reduce_kernel(
    const float* __restrict__ partials, float* __restrict__ out) {
  __shared__ float red[4];
  int tid = threadIdx.x;
  float a = (partials[tid] + partials[tid + 256]) +
            (partials[tid + 512] + partials[tid + 768]);
#pragma unroll
  for (int off = 1; off < 64; off <<= 1) a += __shfl_xor(a, off);
  if ((tid & 63) == 0) red[tid >> 6] = a;
  __syncthreads();
  if (tid == 0) out[0] = ((red[0] + red[1]) + (red[2] + red[3])) * (1.0f / BATCH);
}

extern "C" void kernel_launch(void* const* d_in, const int* in_sizes, int n_in,
                              void* d_out, int out_size, void* d_ws, size_t ws_size,
                              hipStream_t stream) {
  const float* tpl = (const float*)d_in[0];
  const float* src = (const float*)d_in[1];
  float* out = (float*)d_out;
  char* ws = (char*)d_ws;

  const size_t ptsBytes = (size_t)BATCH * NPTS * sizeof(float4);   // 512 KB
  const size_t potBytes = (size_t)BATCH * NPTS * sizeof(float);    // 128 KB
  float4* Xp = (float4*)ws;
  float4* Yp = (float4*)(ws + ptsBytes);
  float*  u2 = (float*)(ws + 2 * ptsBytes);
  float*  v2 = (float*)(ws + 2 * ptsBytes + potBytes);
  float*  partials = (float*)(ws + 2 * ptsBytes + 2 * potBytes);   // 4 KB

  const int nblk = BATCH * 64;   // 1024

  prep_kernel<<<(BATCH * NPTS + 255) / 256, 256, 0, stream>>>(tpl, src, Xp, Yp, v2);
  for (int it = 0; it < 50; ++it) {
    sink_half<<<nblk, 256, 0, stream>>>(Xp, Yp, v2, u2);   // f-update
    sink_half<<<nblk, 256, 0, stream>>>(Yp, Xp, u2, v2);   // g-update
  }
  final_kernel<<<nblk, 256, 0, stream>>>(Xp, Yp, u2, v2, partials);
  reduce_kernel<<<1, 256, 0, stream>>>(partials, out);
}

// Round 4
// 2175.280 us; speedup vs baseline: 1.3146x; 1.3146x over previous
//
#include <hip/hip_runtime.h>
#include <hip/hip_bf16.h>

// EMD via Sinkhorn (EPS=0.02, 50 iters), B=16, N=M=2048, 3-D points.
// Potentials in base-2 log domain scaled by 1/EPS:
//   u2 = (f/EPS)*log2(e), v2 = (g/EPS)*log2(e)
// Half-iteration with per-row static shift c[n] = KSCALE*dmin[n]:
//   u2[n] = -log2(N) + c[n] - log2( sum_m 2^(v2[m] - d(n,m)*KSCALE + c[n]) )
// Shift guarantees max term >= 2^(v[nn]) (no total underflow -> no -inf),
// computed ONCE by a dmin pre-pass (amortized over 100 dispatches).
// Loss: (1/B) * sum_{b,n,m} 2^(u2[n]+v2[m]-d*KSCALE) * d
//
// R1: LDS-BW theory -> 4 rows/thread: no change (not LDS-bound).
// R3: plain sum NaN'd (full-row underflow for isolated rows).
// R4: dmin shift (no online max, no serial chain) + float2 packed math
//     (v_pk_fma_f32) for the distance arithmetic.

#define BATCH 16
#define NPTS 2048
#define RPB 32           // rows per block
#define RPT 4            // rows per thread (2 float2 pairs)
#define KU 4             // column unroll per J-iteration
#define KSCALE 72.13475204444817f   // (1/0.02) * log2(e)
#define NEG_LOG2N (-11.0f)          // -log2(2048)

typedef float v2f __attribute__((ext_vector_type(2)));

#if __has_builtin(__builtin_amdgcn_exp2f)
#define EX2(x) __builtin_amdgcn_exp2f(x)
#else
#define EX2(x) exp2f(x)
#endif
#if __has_builtin(__builtin_amdgcn_logf)
#define LG2(x) __builtin_amdgcn_logf(x)
#else
#define LG2(x) log2f(x)
#endif
#if __has_builtin(__builtin_amdgcn_sqrtf)
#define SQRTF(x) __builtin_amdgcn_sqrtf(x)
#else
#define SQRTF(x) sqrtf(x)
#endif
#define VMIN(a, b) __builtin_elementwise_min(a, b)

__global__ __launch_bounds__(256) void prep_kernel(
    const float* __restrict__ tpl, const float* __restrict__ src,
    float4* __restrict__ Xp, float4* __restrict__ Yp, float* __restrict__ v2) {
  int i = blockIdx.x * 256 + threadIdx.x;
  if (i < BATCH * NPTS) {
    float x0 = tpl[3*i], x1 = tpl[3*i+1], x2 = tpl[3*i+2];
    Xp[i] = make_float4(x0, x1, x2, x0*x0 + x1*x1 + x2*x2);
    float y0 = src[3*i], y1 = src[3*i+1], y2 = src[3*i+2];
    Yp[i] = make_float4(y0, y1, y2, y0*y0 + y1*y1 + y2*y2);
    v2[i] = 0.0f;
  }
}

// Pre-pass: cshift[n] = KSCALE * min_m d(n,m), for rows from Rp vs columns Cp.
__global__ __launch_bounds__(256, 4) void dmin_kernel(
    const float4* __restrict__ Rp, const float4* __restrict__ Cp,
    float* __restrict__ cshift) {
  __shared__ float4 sY[NPTS];   // 32 KB
  int bx = blockIdx.x;
  int b = bx >> 6;
  int rblk = bx & 63;
  int tid = threadIdx.x;
  const float4* cb = Cp + b * NPTS;
  for (int i = tid; i < NPTS; i += 256) sY[i] = cb[i];
  __syncthreads();

  int rg = tid >> 5, lane = tid & 31;
  int nbase = rblk * RPB + rg * RPT;

  v2f xx[2], xy[2], xz[2], xw[2], msq[2];
#pragma unroll
  for (int p = 0; p < 2; ++p) {
    float4 a = Rp[b * NPTS + nbase + 2*p];
    float4 c = Rp[b * NPTS + nbase + 2*p + 1];
    xx[p] = (v2f){a.x, c.x}; xy[p] = (v2f){a.y, c.y};
    xz[p] = (v2f){a.z, c.z}; xw[p] = (v2f){a.w, c.w};
    msq[p] = (v2f){1e30f, 1e30f};
  }

  for (int J = 0; J < NPTS / (32 * KU); ++J) {
    float4 yp[KU];
#pragma unroll
    for (int k = 0; k < KU; ++k) yp[k] = sY[J * (32 * KU) + k * 32 + lane];
#pragma unroll
    for (int k = 0; k < KU; ++k) {
#pragma unroll
      for (int p = 0; p < 2; ++p) {
        v2f dot = xx[p] * yp[k].x;
        dot = xy[p] * yp[k].y + dot;
        dot = xz[p] * yp[k].z + dot;
        v2f sq = xw[p] + yp[k].w;
        sq = dot * (-2.0f) + sq;
        msq[p] = VMIN(msq[p], sq);
      }
    }
  }
  float s[RPT] = { msq[0].x, msq[0].y, msq[1].x, msq[1].y };
#pragma unroll
  for (int off = 1; off < 32; off <<= 1) {
#pragma unroll
    for (int r = 0; r < RPT; ++r) s[r] = fminf(s[r], __shfl_xor(s[r], off));
  }
  if (lane == 0) {
#pragma unroll
    for (int r = 0; r < RPT; ++r)
      cshift[b * NPTS + nbase + r] = KSCALE * SQRTF(fmaxf(s[r], 1e-12f));
  }
}

// One Sinkhorn half-step for 32 rows of batch b:
//   wout[n] = -log2(N) + c[n] - log2( sum_m 2^(win[m] - d(n,m)*KSCALE + c[n]) )
// Symmetric: (Xp,Yp,v2,cX,u2) for f-update, (Yp,Xp,u2,cY,v2) for g-update.
__global__ __launch_bounds__(256, 4) void sink_half(
    const float4* __restrict__ Rp,   // points whose potentials we update
    const float4* __restrict__ Cp,   // points scanned (columns)
    const float* __restrict__ win,   // incoming potential (base-2, scaled)
    const float* __restrict__ crow,  // per-row shift KSCALE*dmin
    float* __restrict__ wout) {
  __shared__ float4 sY[NPTS];   // 32 KB
  __shared__ float  sv[NPTS];   // 8 KB
  int bx = blockIdx.x;
  int b = bx >> 6;
  int rblk = bx & 63;
  int tid = threadIdx.x;
  const float4* cb = Cp + b * NPTS;
  const float*  vb = win + b * NPTS;
  for (int i = tid; i < NPTS; i += 256) { sY[i] = cb[i]; sv[i] = vb[i]; }
  __syncthreads();

  int rg = tid >> 5, lane = tid & 31;
  int nbase = rblk * RPB + rg * RPT;

  v2f xx[2], xy[2], xz[2], xw[2], csh[2], acc[2];
#pragma unroll
  for (int p = 0; p < 2; ++p) {
    float4 a = Rp[b * NPTS + nbase + 2*p];
    float4 c = Rp[b * NPTS + nbase + 2*p + 1];
    xx[p] = (v2f){a.x, c.x}; xy[p] = (v2f){a.y, c.y};
    xz[p] = (v2f){a.z, c.z}; xw[p] = (v2f){a.w, c.w};
    csh[p] = (v2f){crow[b * NPTS + nbase + 2*p], crow[b * NPTS + nbase + 2*p + 1]};
    acc[p] = (v2f){0.0f, 0.0f};
  }

  for (int J = 0; J < NPTS / (32 * KU); ++J) {   // 16 iterations
    float4 yp[KU];
    float  vm[KU];
#pragma unroll
    for (int k = 0; k < KU; ++k) {
      int m = J * (32 * KU) + k * 32 + lane;
      yp[k] = sY[m];
      vm[k] = sv[m];
    }
#pragma unroll
    for (int k = 0; k < KU; ++k) {
#pragma unroll
      for (int p = 0; p < 2; ++p) {
        v2f dot = xx[p] * yp[k].x;
        dot = xy[p] * yp[k].y + dot;
        dot = xz[p] * yp[k].z + dot;
        v2f sq = xw[p] + yp[k].w;
        sq = dot * (-2.0f) + sq;
        float d0 = SQRTF(fmaxf(sq.x, 1e-12f));
        float d1 = SQRTF(fmaxf(sq.y, 1e-12f));
        v2f arg = (v2f){d0, d1} * (-KSCALE) + (csh[p] + vm[k]);
        acc[p] += (v2f){EX2(arg.x), EX2(arg.y)};
      }
    }
  }

  float s[RPT] = { acc[0].x, acc[0].y, acc[1].x, acc[1].y };
#pragma unroll
  for (int off = 1; off < 32; off <<= 1) {
#pragma unroll
    for (int r = 0; r < RPT; ++r) s[r] += __shfl_xor(s[r], off);
  }
  if (lane == 0) {
#pragma unroll
    for (int r = 0; r < RPT; ++r)
      wout[b * NPTS + nbase + r] =
          NEG_LOG2N + crow[b * NPTS + nbase + r] - LG2(s[r]);
  }
}

// Final pass: partial[block] = sum over this block's 32 rows of sum_m 2^(u2+v2-d*K)*d
// (P entries bounded by ~2^-11 scale; plain accumulation is safe here.)
__global__ __launch_bounds__(256, 4) void final_kernel(
    const float4* __restrict__ Xp, const float4* __restrict__ Yp,
    const float* __restrict__ u2, const float* __restrict__ v2,
    float* __restrict__ partials) {
  __shared__ float4 sY[NPTS];   // 32 KB
  __shared__ float  sv[NPTS];   // 8 KB
  __shared__ float  red[8];
  int bx = blockIdx.x;
  int b = bx >> 6;
  int rblk = bx & 63;
  int tid = threadIdx.x;
  const float4* cb = Yp + b * NPTS;
  const float*  vb = v2 + b * NPTS;
  for (int i = tid; i < NPTS; i += 256) { sY[i] = cb[i]; sv[i] = vb[i]; }
  __syncthreads();

  int rg = tid >> 5, lane = tid & 31;
  int nbase = rblk * RPB + rg * RPT;

  float4 xp[RPT];
  float un[RPT], acc[RPT];
#pragma unroll
  for (int r = 0; r < RPT; ++r) {
    xp[r] = Xp[b * NPTS + nbase + r];
    un[r] = u2[b * NPTS + nbase + r];
    acc[r] = 0.0f;
  }

  for (int J = 0; J < NPTS / (32 * KU); ++J) {
    float4 yp[KU];
    float  vm[KU];
#pragma unroll
    for (int k = 0; k < KU; ++k) {
      int m = J * (32 * KU) + k * 32 + lane;
      yp[k] = sY[m];
      vm[k] = sv[m];
    }
#pragma unroll
    for (int k = 0; k < KU; ++k) {
#pragma unroll
      for (int r = 0; r < RPT; ++r) {
        float dot = fmaf(xp[r].z, yp[k].z, fmaf(xp[r].y, yp[k].y, xp[r].x * yp[k].x));
        float sq  = fmaf(-2.0f, dot, xp[r].w + yp[k].w);
        float d   = SQRTF(fmaxf(sq, 1e-12f));
        float e   = EX2(fmaf(d, -KSCALE, un[r] + vm[k]));
        acc[r] = fmaf(e, d, acc[r]);
      }
    }
  }
  float a = (acc[0] + acc[1]) + (acc[2] + acc[3]);
#pragma unroll
  for (int off = 1; off < 32; off <<= 1) a += __shfl_xor(a, off);
  if (lane == 0) red[rg] = a;
  __syncthreads();
  if (tid == 0) {
    float sblk = 0.0f;
#pragma unroll
    for (int i = 0; i < 8; ++i) sblk += red[i];
    partials[bx] = sblk;
  }
}

__global__ __launch_bounds__(256) void reduce_kernel(
    const float* __restrict__ partials, float* __restrict__ out) {
  __shared__ float red[4];
  int tid = threadIdx.x;
  float a = (partials[tid] + partials[tid + 256]) +
            (partials[tid + 512] + partials[tid + 768]);
#pragma unroll
  for (int off = 1; off < 64; off <<= 1) a += __shfl_xor(a, off);
  if ((tid & 63) == 0) red[tid >> 6] = a;
  __syncthreads();
  if (tid == 0) out[0] = ((red[0] + red[1]) + (red[2] + red[3])) * (1.0f / BATCH);
}

extern "C" void kernel_launch(void* const* d_in, const int* in_sizes, int n_in,
                              void* d_out, int out_size, void* d_ws, size_t ws_size,
                              hipStream_t stream) {
  const float* tpl = (const float*)d_in[0];
  const float* src = (const float*)d_in[1];
  float* out = (float*)d_out;
  char* ws = (char*)d_ws;

  const size_t ptsBytes = (size_t)BATCH * NPTS * sizeof(float4);   // 512 KB
  const size_t potBytes = (size_t)BATCH * NPTS * sizeof(float);    // 128 KB
  float4* Xp = (float4*)ws;
  float4* Yp = (float4*)(ws + ptsBytes);
  float*  u2 = (float*)(ws + 2 * ptsBytes);
  float*  v2 = (float*)(ws + 2 * ptsBytes + potBytes);
  float*  cX = (float*)(ws + 2 * ptsBytes + 2 * potBytes);
  float*  cY = (float*)(ws + 2 * ptsBytes + 3 * potBytes);
  float*  partials = (float*)(ws + 2 * ptsBytes + 4 * potBytes);   // 4 KB

  const int nblk = BATCH * 64;   // 1024

  prep_kernel<<<(BATCH * NPTS + 255) / 256, 256, 0, stream>>>(tpl, src, Xp, Yp, v2);
  dmin_kernel<<<nblk, 256, 0, stream>>>(Xp, Yp, cX);
  dmin_kernel<<<nblk, 256, 0, stream>>>(Yp, Xp, cY);
  for (int it = 0; it < 50; ++it) {
    sink_half<<<nblk, 256, 0, stream>>>(Xp, Yp, v2, cX, u2);   // f-update
    sink_half<<<nblk, 256, 0, stream>>>(Yp, Xp, u2, cY, v2);   // g-update
  }
  final_kernel<<<nblk, 256, 0, stream>>>(Xp, Yp, u2, v2, partials);
  reduce_kernel<<<1, 256, 0, stream>>>(partials, out);
}